// Round 1
// baseline (829.585 us; speedup 1.0000x reference)
//
#include <hip/hip_runtime.h>
#include <math.h>

#define N_ROWS 32768
#define DIM 256
#define K_CODES 1024

// ---- workspace float offsets (total ~1.2 MB) ----
#define WS_LOSS   0
#define WS_NSUM   1
#define WS_COUNTS 64
#define WS_ZZ     2048
#define WS_EE     34816
#define WS_ESUM   36864
#define WS_TOTAL  (36864 + K_CODES * DIM)   // 299008 floats

// ---- output float offsets (return-order concatenation) ----
#define OFF_ZQ    0ull
#define OFF_CODES 8388608ull
#define OFF_LOSS  8421376ull
#define OFF_PERP  8421377ull
#define OFF_ENT   8421378ull
#define OFF_SOFT  8421379ull          // NOTE: %4==3 -> scalar access only in this region
#define OFF_NEMB  41975811ull
#define OFF_NCS   42237955ull
#define OFF_NEA   42238979ull

__global__ __launch_bounds__(256) void k0_zero(float* ws) {
    int i = blockIdx.x * 256 + threadIdx.x;
    if (i < WS_TOTAL) ws[i] = 0.0f;
}

// one wave per row: zz[n]=||z_n||^2 for rows < N_ROWS, ee[k]=||e_k||^2 otherwise
__global__ __launch_bounds__(256) void k1_norms(const float* __restrict__ z,
                                                const float* __restrict__ embed,
                                                float* __restrict__ ws) {
    int wave = threadIdx.x >> 6;
    int lane = threadIdx.x & 63;
    int row = blockIdx.x * 4 + wave;
    const float* src = (row < N_ROWS) ? (z + (size_t)row * DIM)
                                      : (embed + (size_t)(row - N_ROWS) * DIM);
    float4 v = *(const float4*)(src + lane * 4);
    float s = v.x * v.x + v.y * v.y + v.z * v.z + v.w * v.w;
    #pragma unroll
    for (int off = 32; off; off >>= 1) s += __shfl_down(s, off, 64);
    if (lane == 0) {
        if (row < N_ROWS) ws[WS_ZZ + row] = s;
        else              ws[WS_EE + (row - N_ROWS)] = s;
    }
}

// dist GEMM: dist[n,k] = (zz[n] - 2*z_n.e_k) + ee[k], written into out soft region.
// BM=BN=128, BD=32, 256 threads, 8x8 micro-tile per thread.
__global__ __launch_bounds__(256) void k2_dist(const float* __restrict__ z,
                                               const float* __restrict__ embed,
                                               const float* __restrict__ ws,
                                               float* __restrict__ out) {
    __shared__ float As[32][132];   // [d][m], +4 pad keeps b128 alignment, light conflicts
    __shared__ float Bs[32][132];   // [d][k_local]
    int tid = threadIdx.x;
    int tx = tid & 15, ty = tid >> 4;
    int rowBase = blockIdx.y * 128;
    int colBase = blockIdx.x * 128;
    int lr  = tid >> 3;        // 0..31
    int lc4 = (tid & 7) * 4;   // 0,4,...,28

    float acc[8][8];
    #pragma unroll
    for (int i = 0; i < 8; ++i)
        #pragma unroll
        for (int j = 0; j < 8; ++j) acc[i][j] = 0.f;

    for (int dt = 0; dt < 8; ++dt) {
        int d0 = dt * 32;
        #pragma unroll
        for (int i = 0; i < 4; ++i) {
            float4 a = *(const float4*)&z[(size_t)(rowBase + lr + 32 * i) * DIM + d0 + lc4];
            float4 b = *(const float4*)&embed[(size_t)(colBase + lr + 32 * i) * DIM + d0 + lc4];
            As[lc4 + 0][lr + 32 * i] = a.x; As[lc4 + 1][lr + 32 * i] = a.y;
            As[lc4 + 2][lr + 32 * i] = a.z; As[lc4 + 3][lr + 32 * i] = a.w;
            Bs[lc4 + 0][lr + 32 * i] = b.x; Bs[lc4 + 1][lr + 32 * i] = b.y;
            Bs[lc4 + 2][lr + 32 * i] = b.z; Bs[lc4 + 3][lr + 32 * i] = b.w;
        }
        __syncthreads();
        #pragma unroll
        for (int d = 0; d < 32; ++d) {
            float4 a0 = *(const float4*)&As[d][ty * 8];
            float4 a1 = *(const float4*)&As[d][ty * 8 + 4];
            float av[8] = {a0.x, a0.y, a0.z, a0.w, a1.x, a1.y, a1.z, a1.w};
            float bv[8];
            #pragma unroll
            for (int j = 0; j < 8; ++j) bv[j] = Bs[d][tx + 16 * j];
            #pragma unroll
            for (int i = 0; i < 8; ++i)
                #pragma unroll
                for (int j = 0; j < 8; ++j) acc[i][j] += av[i] * bv[j];
        }
        __syncthreads();
    }
    #pragma unroll
    for (int i = 0; i < 8; ++i) {
        int n = rowBase + ty * 8 + i;
        float zzn = ws[WS_ZZ + n];
        float* orow = out + OFF_SOFT + (size_t)n * K_CODES + colBase;
        #pragma unroll
        for (int j = 0; j < 8; ++j) {
            int kk = tx + 16 * j;  // coalesced 64B segments per (i,j) store
            float eek = ws[WS_EE + colBase + kk];
            orow[kk] = (zzn - 2.0f * acc[i][j]) + eek;   // numpy assoc order
        }
    }
}

__device__ inline void blockMinIdx(float& v, int& idx, float* smv, int* smi) {
    int lane = threadIdx.x & 63, wave = threadIdx.x >> 6;
    #pragma unroll
    for (int off = 32; off; off >>= 1) {
        float ov = __shfl_down(v, off, 64);
        int   oi = __shfl_down(idx, off, 64);
        if (ov < v || (ov == v && oi < idx)) { v = ov; idx = oi; }
    }
    if (lane == 0) { smv[wave] = v; smi[wave] = idx; }
    __syncthreads();
    v = smv[0]; idx = smi[0];
    #pragma unroll
    for (int w = 1; w < 4; ++w) {
        float ov = smv[w]; int oi = smi[w];
        if (ov < v || (ov == v && oi < idx)) { v = ov; idx = oi; }
    }
    __syncthreads();
}

__device__ inline float blockSum(float v, float* sm) {
    int lane = threadIdx.x & 63, wave = threadIdx.x >> 6;
    #pragma unroll
    for (int off = 32; off; off >>= 1) v += __shfl_down(v, off, 64);
    if (lane == 0) sm[wave] = v;
    __syncthreads();
    float r = sm[0] + sm[1] + sm[2] + sm[3];
    __syncthreads();
    return r;
}

// per-row: argmin (+fp64 near-tie refinement), in-place softmax, z_q, loss, EMA stats
__global__ __launch_bounds__(256) void k3_softmax(const float* __restrict__ z,
                                                  const float* __restrict__ embed,
                                                  float* __restrict__ ws,
                                                  float* __restrict__ out) {
    __shared__ float smv[4];
    __shared__ int   smi[4];
    __shared__ float sms[4];
    __shared__ double sdd[4];
    __shared__ int cand[8];
    __shared__ int ncand;

    int n = blockIdx.x;
    int tid = threadIdx.x;
    float* dptr = out + OFF_SOFT + (size_t)n * K_CODES;

    float d[4];
    float lmin = 3.4e38f; int lidx = 0;
    #pragma unroll
    for (int j = 0; j < 4; ++j) {
        int k = tid + 256 * j;
        d[j] = dptr[k];
        if (d[j] < lmin) { lmin = d[j]; lidx = k; }
    }
    float bmin = lmin; int code = lidx;
    blockMinIdx(bmin, code, smv, smi);

    // near-tie candidates: anything within 1e-3 of min (>> fp32 dist error ~5e-5)
    if (tid == 0) ncand = 0;
    __syncthreads();
    #pragma unroll
    for (int j = 0; j < 4; ++j) {
        if (d[j] <= bmin + 1e-3f) {
            int slot = atomicAdd(&ncand, 1);
            if (slot < 8) cand[slot] = tid + 256 * j;
        }
    }
    __syncthreads();
    int nc = ncand;
    float zv = z[(size_t)n * DIM + tid];
    if (nc > 1) {   // rare path: refine with fp64 dot, numpy-style fp32 final rounding
        int lim = nc < 8 ? nc : 8;
        float zzn = ws[WS_ZZ + n];
        float bestd = 0.f; int bestk = -1;
        for (int c = 0; c < lim; ++c) {
            int kc = cand[c];
            double part = (double)zv * (double)embed[(size_t)kc * DIM + tid];
            int lane = tid & 63, wave = tid >> 6;
            #pragma unroll
            for (int off = 32; off; off >>= 1) part += __shfl_down(part, off, 64);
            if (lane == 0) sdd[wave] = part;
            __syncthreads();
            double dot = sdd[0] + sdd[1] + sdd[2] + sdd[3];
            __syncthreads();
            float d32 = (zzn - 2.0f * (float)dot) + ws[WS_EE + kc];
            if (bestk < 0 || d32 < bestd || (d32 == bestd && kc < bestk)) { bestd = d32; bestk = kc; }
        }
        code = bestk;   // identical on all threads
    }

    // softmax (shift by bmin is exact-invariant)
    float p[4]; float s = 0.f;
    #pragma unroll
    for (int j = 0; j < 4; ++j) { p[j] = __expf((bmin - d[j]) * 10.0f); s += p[j]; }
    float tot = blockSum(s, sms);
    float inv = 1.0f / tot;
    #pragma unroll
    for (int j = 0; j < 4; ++j) dptr[tid + 256 * j] = p[j] * inv;

    float qv = embed[(size_t)code * DIM + tid];
    out[OFF_ZQ + (size_t)n * DIM + tid] = qv;
    float diff = zv - qv;
    float lsum = blockSum(diff * diff, sms);
    atomicAdd(&ws[WS_ESUM + (size_t)code * DIM + tid], zv);
    if (tid == 0) {
        atomicAdd(&ws[WS_LOSS], lsum);
        atomicAdd(&ws[WS_COUNTS + code], 1.0f);
        out[OFF_CODES + n] = (float)code;
    }
}

__global__ __launch_bounds__(1024) void k4a_stats(const float* __restrict__ cluster_size,
                                                  float* __restrict__ ws,
                                                  float* __restrict__ out) {
    __shared__ float sm[16];
    int k = threadIdx.x;
    int lane = k & 63, wave = k >> 6;
    float cnt = ws[WS_COUNTS + k];
    float ncs = 0.99f * cluster_size[k] + 0.01f * cnt;
    out[OFF_NCS + k] = ncs;

    float v = ncs;
    #pragma unroll
    for (int off = 32; off; off >>= 1) v += __shfl_down(v, off, 64);
    if (lane == 0) sm[wave] = v;
    __syncthreads();
    if (k == 0) {
        float nsum = 0.f;
        for (int w = 0; w < 16; ++w) nsum += sm[w];
        ws[WS_NSUM] = nsum;
    }
    __syncthreads();

    float avg = cnt / (float)N_ROWS;
    float ent_t = -avg * logf(avg + 1e-10f);
    v = ent_t;
    #pragma unroll
    for (int off = 32; off; off >>= 1) v += __shfl_down(v, off, 64);
    if (lane == 0) sm[wave] = v;
    __syncthreads();
    if (k == 0) {
        float ent = 0.f;
        for (int w = 0; w < 16; ++w) ent += sm[w];
        out[OFF_ENT]  = ent;
        out[OFF_PERP] = expf(ent);
        out[OFF_LOSS] = ws[WS_LOSS] / 8388608.0f;
    }
}

__global__ __launch_bounds__(256) void k4b_embed(const float* __restrict__ embed_avg,
                                                 const float* __restrict__ ws,
                                                 float* __restrict__ out) {
    int k = blockIdx.x, d = threadIdx.x;
    float es  = ws[WS_ESUM + (size_t)k * DIM + d];
    float nea = 0.99f * embed_avg[(size_t)k * DIM + d] + 0.01f * es;
    out[OFF_NEA + (size_t)k * DIM + d] = nea;
    float ncs  = out[OFF_NCS + k];
    float nsum = ws[WS_NSUM];
    float csn  = (ncs + 1e-5f) / (nsum + K_CODES * 1e-5f) * nsum;
    out[OFF_NEMB + (size_t)k * DIM + d] = nea / csn;
}

extern "C" void kernel_launch(void* const* d_in, const int* in_sizes, int n_in,
                              void* d_out, int out_size, void* d_ws, size_t ws_size,
                              hipStream_t stream) {
    const float* z            = (const float*)d_in[0];
    const float* embed        = (const float*)d_in[1];
    const float* cluster_size = (const float*)d_in[2];
    const float* embed_avg    = (const float*)d_in[3];
    float* out = (float*)d_out;
    float* ws  = (float*)d_ws;

    k0_zero<<<(WS_TOTAL + 255) / 256, 256, 0, stream>>>(ws);
    k1_norms<<<(N_ROWS + K_CODES) / 4, 256, 0, stream>>>(z, embed, ws);
    k2_dist<<<dim3(8, 256), 256, 0, stream>>>(z, embed, ws, out);
    k3_softmax<<<N_ROWS, 256, 0, stream>>>(z, embed, ws, out);
    k4a_stats<<<1, 1024, 0, stream>>>(cluster_size, ws, out);
    k4b_embed<<<K_CODES, 256, 0, stream>>>(embed_avg, ws, out);
}

// Round 6
// 471.601 us; speedup vs baseline: 1.7591x; 1.7591x over previous
//
#include <hip/hip_runtime.h>
#include <math.h>

#define N_ROWS 32768
#define DIM 256
#define K_CODES 1024

// ---- workspace float offsets (total ~1.2 MB) ----
#define WS_LOSS   0        // 1024 distributed loss slots
#define WS_NSUM   1024
#define WS_ZZ     2048     // 32768
#define WS_EE     34816    // 1024
#define WS_COUNTS 35840    // 1024
#define WS_ESUM   36864    // 1024*256
#define WS_TOTAL  (36864 + K_CODES * DIM)   // 299008 floats

// ---- output float offsets (return-order concatenation) ----
#define OFF_ZQ    0ull
#define OFF_CODES 8388608ull
#define OFF_LOSS  8421376ull
#define OFF_PERP  8421377ull
#define OFF_ENT   8421378ull
#define OFF_SOFT  8421379ull          // %4==3 -> scalar access in this region (R1-style)
#define OFF_NEMB  41975811ull
#define OFF_NCS   42237955ull
#define OFF_NEA   42238979ull

__global__ __launch_bounds__(256) void k0_zero(float* ws) {
    int i = blockIdx.x * 256 + threadIdx.x;
    if (i < WS_TOTAL) ws[i] = 0.0f;
}

// one wave per row: zz[n]=||z_n||^2 for rows < N_ROWS, ee[k]=||e_k||^2 otherwise
__global__ __launch_bounds__(256) void k1_norms(const float* __restrict__ z,
                                                const float* __restrict__ embed,
                                                float* __restrict__ ws) {
    int wave = threadIdx.x >> 6;
    int lane = threadIdx.x & 63;
    int row = blockIdx.x * 4 + wave;
    const float* src = (row < N_ROWS) ? (z + (size_t)row * DIM)
                                      : (embed + (size_t)(row - N_ROWS) * DIM);
    float4 v = *(const float4*)(src + lane * 4);
    float s = v.x * v.x + v.y * v.y + v.z * v.z + v.w * v.w;
    #pragma unroll
    for (int off = 32; off; off >>= 1) s += __shfl_down(s, off, 64);
    if (lane == 0) {
        if (row < N_ROWS) ws[WS_ZZ + row] = s;
        else              ws[WS_EE + (row - N_ROWS)] = s;
    }
}

// dist GEMM (exact R1 version, known-good): dist[n,k] = (zz[n] - 2*z_n.e_k) + ee[k]
// BM=BN=128, BD=32, 256 threads, 8x8 micro-tile per thread.
__global__ __launch_bounds__(256) void k2_dist(const float* __restrict__ z,
                                               const float* __restrict__ embed,
                                               const float* __restrict__ ws,
                                               float* __restrict__ out) {
    __shared__ float As[32][132];
    __shared__ float Bs[32][132];
    int tid = threadIdx.x;
    int tx = tid & 15, ty = tid >> 4;
    int rowBase = blockIdx.y * 128;
    int colBase = blockIdx.x * 128;
    int lr  = tid >> 3;        // 0..31
    int lc4 = (tid & 7) * 4;   // 0,4,...,28

    float acc[8][8];
    #pragma unroll
    for (int i = 0; i < 8; ++i)
        #pragma unroll
        for (int j = 0; j < 8; ++j) acc[i][j] = 0.f;

    for (int dt = 0; dt < 8; ++dt) {
        int d0 = dt * 32;
        #pragma unroll
        for (int i = 0; i < 4; ++i) {
            float4 a = *(const float4*)&z[(size_t)(rowBase + lr + 32 * i) * DIM + d0 + lc4];
            float4 b = *(const float4*)&embed[(size_t)(colBase + lr + 32 * i) * DIM + d0 + lc4];
            As[lc4 + 0][lr + 32 * i] = a.x; As[lc4 + 1][lr + 32 * i] = a.y;
            As[lc4 + 2][lr + 32 * i] = a.z; As[lc4 + 3][lr + 32 * i] = a.w;
            Bs[lc4 + 0][lr + 32 * i] = b.x; Bs[lc4 + 1][lr + 32 * i] = b.y;
            Bs[lc4 + 2][lr + 32 * i] = b.z; Bs[lc4 + 3][lr + 32 * i] = b.w;
        }
        __syncthreads();
        #pragma unroll
        for (int d = 0; d < 32; ++d) {
            float4 a0 = *(const float4*)&As[d][ty * 8];
            float4 a1 = *(const float4*)&As[d][ty * 8 + 4];
            float av[8] = {a0.x, a0.y, a0.z, a0.w, a1.x, a1.y, a1.z, a1.w};
            float bv[8];
            #pragma unroll
            for (int j = 0; j < 8; ++j) bv[j] = Bs[d][tx + 16 * j];
            #pragma unroll
            for (int i = 0; i < 8; ++i)
                #pragma unroll
                for (int j = 0; j < 8; ++j) acc[i][j] += av[i] * bv[j];
        }
        __syncthreads();
    }
    #pragma unroll
    for (int i = 0; i < 8; ++i) {
        int n = rowBase + ty * 8 + i;
        float zzn = ws[WS_ZZ + n];
        float* orow = out + OFF_SOFT + (size_t)n * K_CODES + colBase;
        #pragma unroll
        for (int j = 0; j < 8; ++j) {
            int kk = tx + 16 * j;
            float eek = ws[WS_EE + colBase + kk];
            orow[kk] = (zzn - 2.0f * acc[i][j]) + eek;
        }
    }
}

__device__ inline void blockMinIdx(float& v, int& idx, float* smv, int* smi) {
    int lane = threadIdx.x & 63, wave = threadIdx.x >> 6;
    #pragma unroll
    for (int off = 32; off; off >>= 1) {
        float ov = __shfl_down(v, off, 64);
        int   oi = __shfl_down(idx, off, 64);
        if (ov < v || (ov == v && oi < idx)) { v = ov; idx = oi; }
    }
    if (lane == 0) { smv[wave] = v; smi[wave] = idx; }
    __syncthreads();
    v = smv[0]; idx = smi[0];
    #pragma unroll
    for (int w = 1; w < 4; ++w) {
        float ov = smv[w]; int oi = smi[w];
        if (ov < v || (ov == v && oi < idx)) { v = ov; idx = oi; }
    }
    __syncthreads();
}

__device__ inline float blockSum(float v, float* sm) {
    int lane = threadIdx.x & 63, wave = threadIdx.x >> 6;
    #pragma unroll
    for (int off = 32; off; off >>= 1) v += __shfl_down(v, off, 64);
    if (lane == 0) sm[wave] = v;
    __syncthreads();
    float r = sm[0] + sm[1] + sm[2] + sm[3];
    __syncthreads();
    return r;
}

// per-row block (exact R1 version, known-good), ONLY change: distributed loss slots.
__global__ __launch_bounds__(256) void k3_softmax(const float* __restrict__ z,
                                                  const float* __restrict__ embed,
                                                  float* __restrict__ ws,
                                                  float* __restrict__ out) {
    __shared__ float smv[4];
    __shared__ int   smi[4];
    __shared__ float sms[4];
    __shared__ double sdd[4];
    __shared__ int cand[8];
    __shared__ int ncand;

    int n = blockIdx.x;
    int tid = threadIdx.x;
    float* dptr = out + OFF_SOFT + (size_t)n * K_CODES;

    float d[4];
    float lmin = 3.4e38f; int lidx = 0;
    #pragma unroll
    for (int j = 0; j < 4; ++j) {
        int k = tid + 256 * j;
        d[j] = dptr[k];
        if (d[j] < lmin) { lmin = d[j]; lidx = k; }
    }
    float bmin = lmin; int code = lidx;
    blockMinIdx(bmin, code, smv, smi);

    // near-tie candidates: anything within 1e-3 of min (>> fp32 dist error ~5e-5)
    if (tid == 0) ncand = 0;
    __syncthreads();
    #pragma unroll
    for (int j = 0; j < 4; ++j) {
        if (d[j] <= bmin + 1e-3f) {
            int slot = atomicAdd(&ncand, 1);
            if (slot < 8) cand[slot] = tid + 256 * j;
        }
    }
    __syncthreads();
    int nc = ncand;
    float zv = z[(size_t)n * DIM + tid];
    if (nc > 1) {   // rare path: refine with fp64 dot, numpy-style fp32 final rounding
        int lim = nc < 8 ? nc : 8;
        float zzn = ws[WS_ZZ + n];
        float bestd = 0.f; int bestk = -1;
        for (int c = 0; c < lim; ++c) {
            int kc = cand[c];
            double part = (double)zv * (double)embed[(size_t)kc * DIM + tid];
            int lane = tid & 63, wave = tid >> 6;
            #pragma unroll
            for (int off = 32; off; off >>= 1) part += __shfl_down(part, off, 64);
            if (lane == 0) sdd[wave] = part;
            __syncthreads();
            double dot = sdd[0] + sdd[1] + sdd[2] + sdd[3];
            __syncthreads();
            float d32 = (zzn - 2.0f * (float)dot) + ws[WS_EE + kc];
            if (bestk < 0 || d32 < bestd || (d32 == bestd && kc < bestk)) { bestd = d32; bestk = kc; }
        }
        code = bestk;   // identical on all threads
    }

    // softmax (shift by bmin is exact-invariant)
    float p[4]; float s = 0.f;
    #pragma unroll
    for (int j = 0; j < 4; ++j) { p[j] = __expf((bmin - d[j]) * 10.0f); s += p[j]; }
    float tot = blockSum(s, sms);
    float inv = 1.0f / tot;
    #pragma unroll
    for (int j = 0; j < 4; ++j) dptr[tid + 256 * j] = p[j] * inv;

    float qv = embed[(size_t)code * DIM + tid];
    out[OFF_ZQ + (size_t)n * DIM + tid] = qv;
    float diff = zv - qv;
    float lsum = blockSum(diff * diff, sms);
    atomicAdd(&ws[WS_ESUM + (size_t)code * DIM + tid], zv);
    if (tid == 0) {
        atomicAdd(&ws[WS_LOSS + (n & 1023)], lsum);   // 1024-way distributed (R1 had 1 slot)
        atomicAdd(&ws[WS_COUNTS + code], 1.0f);
        out[OFF_CODES + n] = (float)code;
    }
}

__global__ __launch_bounds__(1024) void k4a_stats(const float* __restrict__ cluster_size,
                                                  float* __restrict__ ws,
                                                  float* __restrict__ out) {
    __shared__ float sm[16];
    int k = threadIdx.x;
    int lane = k & 63, wave = k >> 6;
    float cnt = ws[WS_COUNTS + k];
    float ncs = 0.99f * cluster_size[k] + 0.01f * cnt;
    out[OFF_NCS + k] = ncs;

    // nsum
    float v = ncs;
    #pragma unroll
    for (int off = 32; off; off >>= 1) v += __shfl_down(v, off, 64);
    if (lane == 0) sm[wave] = v;
    __syncthreads();
    if (k == 0) {
        float t = 0.f;
        for (int w = 0; w < 16; ++w) t += sm[w];
        ws[WS_NSUM] = t;
    }
    __syncthreads();

    // entropy
    float avg = cnt / (float)N_ROWS;
    v = -avg * logf(avg + 1e-10f);
    #pragma unroll
    for (int off = 32; off; off >>= 1) v += __shfl_down(v, off, 64);
    if (lane == 0) sm[wave] = v;
    __syncthreads();
    if (k == 0) {
        float ent = 0.f;
        for (int w = 0; w < 16; ++w) ent += sm[w];
        out[OFF_ENT]  = ent;
        out[OFF_PERP] = expf(ent);
    }
    __syncthreads();

    // loss: sum the 1024 distributed slots
    v = ws[WS_LOSS + k];
    #pragma unroll
    for (int off = 32; off; off >>= 1) v += __shfl_down(v, off, 64);
    if (lane == 0) sm[wave] = v;
    __syncthreads();
    if (k == 0) {
        float t = 0.f;
        for (int w = 0; w < 16; ++w) t += sm[w];
        out[OFF_LOSS] = t / 8388608.0f;
    }
}

__global__ __launch_bounds__(256) void k4b_embed(const float* __restrict__ embed_avg,
                                                 const float* __restrict__ ws,
                                                 float* __restrict__ out) {
    int k = blockIdx.x, d = threadIdx.x;
    float es  = ws[WS_ESUM + (size_t)k * DIM + d];
    float nea = 0.99f * embed_avg[(size_t)k * DIM + d] + 0.01f * es;
    out[OFF_NEA + (size_t)k * DIM + d] = nea;
    float ncs  = out[OFF_NCS + k];
    float nsum = ws[WS_NSUM];
    float csn  = (ncs + 1e-5f) / (nsum + K_CODES * 1e-5f) * nsum;
    out[OFF_NEMB + (size_t)k * DIM + d] = nea / csn;
}

extern "C" void kernel_launch(void* const* d_in, const int* in_sizes, int n_in,
                              void* d_out, int out_size, void* d_ws, size_t ws_size,
                              hipStream_t stream) {
    const float* z            = (const float*)d_in[0];
    const float* embed        = (const float*)d_in[1];
    const float* cluster_size = (const float*)d_in[2];
    const float* embed_avg    = (const float*)d_in[3];
    float* out = (float*)d_out;
    float* ws  = (float*)d_ws;

    k0_zero<<<(WS_TOTAL + 255) / 256, 256, 0, stream>>>(ws);
    k1_norms<<<(N_ROWS + K_CODES) / 4, 256, 0, stream>>>(z, embed, ws);
    k2_dist<<<dim3(8, 256), 256, 0, stream>>>(z, embed, ws, out);
    k3_softmax<<<N_ROWS, 256, 0, stream>>>(z, embed, ws, out);
    k4a_stats<<<1, 1024, 0, stream>>>(cluster_size, ws, out);
    k4b_embed<<<K_CODES, 256, 0, stream>>>(embed_avg, ws, out);
}